// Round 14
// baseline (47.692 us; speedup 1.0000x reference)
//
#include <hip/hip_runtime.h>

#define HD 32
#define DP 12    // x prefetch ring depth; T (=168) divisible by DP
#define REDUN 4  // redundant blocks per tile (DVFS activity test; same-value writes)

typedef __attribute__((ext_vector_type(8))) short bf16x8;
typedef __attribute__((ext_vector_type(4))) float f32x4;

__device__ __forceinline__ int cvtpk_bf16(float a, float b) {
    int r;
    asm("v_cvt_pk_bf16_f32 %0, %1, %2" : "=v"(r) : "v"(a), "v"(b));
    return r;  // [bf16(b) | bf16(a)], a in low half
}

__device__ __forceinline__ void split_pair(float a, float b, int& hi, int& lo) {
    hi = cvtpk_bf16(a, b);
    float fa = __int_as_float(hi << 16);
    float fb = __int_as_float((unsigned)hi & 0xffff0000u);
    lo = cvtpk_bf16(a - fa, b - fb);
}

__device__ __forceinline__ bf16x8 pack4(int w0, int w1, int w2, int w3) {
    union { int i[4]; bf16x8 v; } u;
    u.i[0] = w0; u.i[1] = w1; u.i[2] = w2; u.i[3] = w3;
    return u.v;
}

// W_hh only: split hi+lo. The recurrence weight MUST keep the residual
// (r8: dropping it -> absmax 1.19 vs threshold 0.059, compounding error).
// C-chaining hi->lo is the cheapest join (r10: parallel+v_add join cost +3us).
__device__ __forceinline__ void split_frag(f32x4 a, f32x4 b, bf16x8& hi, bf16x8& lo) {
    int h0,h1,h2,h3,l0,l1,l2,l3;
    split_pair(a[0], a[1], h0, l0);
    split_pair(a[2], a[3], h1, l1);
    split_pair(b[0], b[1], h2, l2);
    split_pair(b[2], b[3], h3, l3);
    hi = pack4(h0,h1,h2,h3);
    lo = pack4(l0,l1,l2,l3);
}

// plain bf16 fragment (RNE) — fine for x, W_ih, h (non-compounding paths)
__device__ __forceinline__ bf16x8 to_bf16_frag(f32x4 a, f32x4 b) {
    return pack4(cvtpk_bf16(a[0], a[1]), cvtpk_bf16(a[2], a[3]),
                 cvtpk_bf16(b[0], b[1]), cvtpk_bf16(b[2], b[3]));
}

// relu on packed bf16 pair: 16-bit sign-monotonic max vs +0 (exact here; r6/r7-proven)
__device__ __forceinline__ int pk_relu(int v) {
    int r;
    asm("v_pk_max_f16 %0, %1, 0" : "=v"(r) : "v"(v));
    return r;
}

// Scalar-base + lane-constant voffset pair load (r5-r7-proven).
__device__ __forceinline__ void gload_pair(f32x4& a, f32x4& b, const float* sbase, int voff) {
    asm volatile("global_load_dwordx4 %0, %2, %3\n\t"
                 "global_load_dwordx4 %1, %2, %3 offset:16"
                 : "=&v"(a), "=&v"(b) : "v"(voff), "s"(sbase));
}

// Counted waits; "+v" ties give consumers true SSA deps on the wait (rule-#18 safe).
#define WAIT_TIE2(N, a, b) \
    asm volatile("s_waitcnt vmcnt(" #N ")" : "+v"(a), "+v"(b))
#define WAIT_TIE4(N, a, b, c, d) \
    asm volatile("s_waitcnt vmcnt(" #N ")" : "+v"(a), "+v"(b), "+v"(c), "+v"(d))

#define MFMA(a,b,c) __builtin_amdgcn_mfma_f32_16x16x32_bf16((a),(b),(c),0,0,0)

// r14 = r7 body VERBATIM (64-thread blocks — the only codegen that has ever
// passed), with REDUN redundant blocks per tile: block i owns tile i % ntiles.
// Redundant blocks do bitwise-identical work and write bitwise-identical bytes
// to the same addresses (deterministic same-value race). Purpose: raise CU
// activity 4x (all SIMDs busy) to test the DVFS-clock hypothesis with zero
// codegen risk. 256-thread packing is banned (r11 wrong, r12/r13 abort).
__global__ __launch_bounds__(64, 1)
void rnn_v14(const float* __restrict__ x,
             const float* __restrict__ h0p,
             const float* __restrict__ W_ih,
             const float* __restrict__ W_hh,
             const float* __restrict__ b_ih,
             const float* __restrict__ b_hh,
             const float* __restrict__ W_out,
             const float* __restrict__ b_out,
             float* __restrict__ out,
             int B, int T, int ntiles)
{
    const int l = threadIdx.x;
    const int q = l >> 4;
    const int c = l & 15;
    const int tile = (int)blockIdx.x % ntiles;
    const int bglob = tile * 16 + c;

    const int rA0 = ((c >> 2) << 3) + (c & 3);   // permuted A-row for MFMA0
    const int rA1 = rA0 + 4;                      // for MFMA1

    // W_hh: split hi+lo (compounding path). W_ih: plain bf16 (r7-proven).
    bf16x8 Whh0h, Whh0l, Whh1h, Whh1l, Wih0, Wih1;
    {
        const f32x4* p;
        p = (const f32x4*)(W_hh + rA0 * HD + q * 8); split_frag(p[0], p[1], Whh0h, Whh0l);
        p = (const f32x4*)(W_hh + rA1 * HD + q * 8); split_frag(p[0], p[1], Whh1h, Whh1l);
        p = (const f32x4*)(W_ih + rA0 * HD + q * 8); Wih0 = to_bf16_frag(p[0], p[1]);
        p = (const f32x4*)(W_ih + rA1 * HD + q * 8); Wih1 = to_bf16_frag(p[0], p[1]);
    }

    f32x4 bias0, bias1;
#pragma unroll
    for (int r = 0; r < 4; ++r) {
        bias0[r] = b_ih[q*8 + r]     + b_hh[q*8 + r];
        bias1[r] = b_ih[q*8 + 4 + r] + b_hh[q*8 + 4 + r];
    }

    // h0 -> plain bf16 B fragment (one-time rounding)
    bf16x8 h_bf;
    {
        const f32x4* p = (const f32x4*)(h0p + (size_t)bglob * HD + q * 8);
        h_bf = to_bf16_frag(p[0], p[1]);
    }

    // lane-constant byte offset; uniform time offset lives in the SGPR base
    const int voff = (int)(((size_t)bglob * T * HD + q * 8) * 4);

    f32x4 xa[DP], xb[DP];
#pragma unroll
    for (int s = 0; s < DP; ++s)
        gload_pair(xa[s], xb[s], x + (size_t)s * HD, voff);

    // xp parity regs: xpA = next even step, xpB = next odd step (2-step slack)
    f32x4 xpA0, xpA1, xpB0, xpB1;
    {
        WAIT_TIE2(22, xa[0], xb[0]);                  // 24 issued, complete pair 0
        bf16x8 xbf = to_bf16_frag(xa[0], xb[0]);
        xpA0 = MFMA(Wih0, xbf, bias0);
        xpA1 = MFMA(Wih1, xbf, bias1);
    }
    {
        WAIT_TIE2(20, xa[1], xb[1]);                  // complete pair 1
        bf16x8 xbf = to_bf16_frag(xa[1], xb[1]);
        xpB0 = MFMA(Wih0, xbf, bias0);
        xpB1 = MFMA(Wih1, xbf, bias1);
    }

    f32x4 hA = {0,0,0,0}, hB = {0,0,0,0};

    // Steady-state ledger (per 2-step group at even t): enter with pairs
    // x[t+2..t+11] in flight (20 loads); issue pairs x[t+12],x[t+13] -> 24;
    // wait vmcnt(20) completes pairs x[t+2],x[t+3]. Lookahead 10 steps.
    for (int t0 = 0; t0 < T; t0 += DP) {
#pragma unroll
        for (int s = 0; s < DP; s += 2) {
            const int t = t0 + s;                     // even
            // ---- recurrence for step t (consumes xpA; hi->lo C-chained) ----
            f32x4 a0 = MFMA(Whh0h, h_bf, xpA0);
            f32x4 a1 = MFMA(Whh1h, h_bf, xpA1);
            a0 = MFMA(Whh0l, h_bf, a0);
            a1 = MFMA(Whh1l, h_bf, a1);

            // ---- refill ring slots s, s+1 with x[t+12], x[t+13] (clamped) ----
            int k1 = t + DP;     k1 = (k1 < T) ? k1 : (T - 1);
            int k2 = t + DP + 1; k2 = (k2 < T) ? k2 : (T - 1);
            gload_pair(xa[s],     xb[s],     x + (size_t)k1 * HD, voff);
            gload_pair(xa[s + 1], xb[s + 1], x + (size_t)k2 * HD, voff);

            // ---- wait for x[t+2], x[t+3] ----
            const int s2 = (s + 2) % DP;
            const int s3 = (s + 3) % DP;
            WAIT_TIE4(20, xa[s2], xb[s2], xa[s3], xb[s3]);

            // ---- xp(t+2) into xpA (off-chain; ~2 steps of slack) ----
            {
                bf16x8 xbf = to_bf16_frag(xa[s2], xb[s2]);
                xpA0 = MFMA(Wih0, xbf, bias0);
                xpA1 = MFMA(Wih1, xbf, bias1);
            }

            // ---- finish step t: pack then packed relu -> h_bf(t+1) ----
            h_bf = pack4(pk_relu(cvtpk_bf16(a0[0], a0[1])),
                         pk_relu(cvtpk_bf16(a0[2], a0[3])),
                         pk_relu(cvtpk_bf16(a1[0], a1[1])),
                         pk_relu(cvtpk_bf16(a1[2], a1[3])));

            // ---- recurrence for step t+1 (consumes xpB) ----
            f32x4 b0 = MFMA(Whh0h, h_bf, xpB0);
            f32x4 b1 = MFMA(Whh1h, h_bf, xpB1);
            b0 = MFMA(Whh0l, h_bf, b0);
            b1 = MFMA(Whh1l, h_bf, b1);

            // ---- xp(t+3) into xpB ----
            {
                bf16x8 xbf = to_bf16_frag(xa[s3], xb[s3]);
                xpB0 = MFMA(Wih0, xbf, bias0);
                xpB1 = MFMA(Wih1, xbf, bias1);
            }

            // ---- finish step t+1 ----
            h_bf = pack4(pk_relu(cvtpk_bf16(b0[0], b0[1])),
                         pk_relu(cvtpk_bf16(b0[2], b0[3])),
                         pk_relu(cvtpk_bf16(b1[0], b1[1])),
                         pk_relu(cvtpk_bf16(b1[2], b1[3])));
            hA = b0; hB = b1;                         // pre-relu f32 of last step
        }
    }

    // epilogue: f32 relu of the final step (keeps hT/pred at full f32 precision)
#pragma unroll
    for (int r = 0; r < 4; ++r) {
        hA[r] = fmaxf(hA[r], 0.0f);
        hB[r] = fmaxf(hB[r], 0.0f);
    }

    // hT: lane holds units q*8+r (hA) and q*8+4+r (hB) of batch c
    float* outh = out + B + (size_t)bglob * HD;
#pragma unroll
    for (int r = 0; r < 4; ++r) {
        outh[q*8 + r]     = hA[r];
        outh[q*8 + 4 + r] = hB[r];
    }
    // pred[b]: partials in lanes {c, c+16, c+32, c+48}
    float p = 0.0f;
#pragma unroll
    for (int r = 0; r < 4; ++r)
        p += hA[r] * W_out[q*8 + r] + hB[r] * W_out[q*8 + 4 + r];
    p += __shfl_xor(p, 16, 64);
    p += __shfl_xor(p, 32, 64);
    if (q == 0) out[bglob] = p + b_out[0];
}

extern "C" void kernel_launch(void* const* d_in, const int* in_sizes, int n_in,
                              void* d_out, int out_size, void* d_ws, size_t ws_size,
                              hipStream_t stream) {
    const float* x      = (const float*)d_in[0];
    const float* hidden = (const float*)d_in[1];
    const float* W_ih   = (const float*)d_in[2];
    const float* W_hh   = (const float*)d_in[3];
    const float* b_ih   = (const float*)d_in[4];
    const float* b_hh   = (const float*)d_in[5];
    const float* W_out  = (const float*)d_in[6];
    const float* b_out  = (const float*)d_in[7];
    float* out = (float*)d_out;

    const int B = in_sizes[1] / HD;          // hidden is (1, B, H)
    const int T = in_sizes[0] / (B * HD);    // x is (B, T, 32); T=168 = 14*DP
    const int ntiles = B / 16;               // 256

    rnn_v14<<<dim3(ntiles * REDUN), dim3(64), 0, stream>>>(
        x, hidden, W_ih, W_hh, b_ih, b_hh, W_out, b_out, out, B, T, ntiles);
}

// Round 15
// 23.129 us; speedup vs baseline: 2.0619x; 2.0619x over previous
//
#include <hip/hip_runtime.h>

#define HD 32
#define DP 12    // x prefetch ring depth; T (=168) divisible by DP

typedef __attribute__((ext_vector_type(8))) short bf16x8;
typedef __attribute__((ext_vector_type(4))) float f32x4;

__device__ __forceinline__ int cvtpk_bf16(float a, float b) {
    int r;
    asm("v_cvt_pk_bf16_f32 %0, %1, %2" : "=v"(r) : "v"(a), "v"(b));
    return r;  // [bf16(b) | bf16(a)], a in low half
}

__device__ __forceinline__ void split_pair(float a, float b, int& hi, int& lo) {
    hi = cvtpk_bf16(a, b);
    float fa = __int_as_float(hi << 16);
    float fb = __int_as_float((unsigned)hi & 0xffff0000u);
    lo = cvtpk_bf16(a - fa, b - fb);
}

__device__ __forceinline__ bf16x8 pack4(int w0, int w1, int w2, int w3) {
    union { int i[4]; bf16x8 v; } u;
    u.i[0] = w0; u.i[1] = w1; u.i[2] = w2; u.i[3] = w3;
    return u.v;
}

// W_hh only: split hi+lo. The recurrence weight MUST keep the residual
// (r8: dropping it -> absmax 1.19 vs threshold 0.059, compounding error).
// C-chaining hi->lo is the cheapest join (r10: parallel+v_add join cost +3us).
__device__ __forceinline__ void split_frag(f32x4 a, f32x4 b, bf16x8& hi, bf16x8& lo) {
    int h0,h1,h2,h3,l0,l1,l2,l3;
    split_pair(a[0], a[1], h0, l0);
    split_pair(a[2], a[3], h1, l1);
    split_pair(b[0], b[1], h2, l2);
    split_pair(b[2], b[3], h3, l3);
    hi = pack4(h0,h1,h2,h3);
    lo = pack4(l0,l1,l2,l3);
}

// plain bf16 fragment (RNE) — fine for x, W_ih, h (non-compounding paths)
__device__ __forceinline__ bf16x8 to_bf16_frag(f32x4 a, f32x4 b) {
    return pack4(cvtpk_bf16(a[0], a[1]), cvtpk_bf16(a[2], a[3]),
                 cvtpk_bf16(b[0], b[1]), cvtpk_bf16(b[2], b[3]));
}

// relu on packed bf16 pair: 16-bit sign-monotonic max vs +0 (exact here; r6/r7-proven)
__device__ __forceinline__ int pk_relu(int v) {
    int r;
    asm("v_pk_max_f16 %0, %1, 0" : "=v"(r) : "v"(v));
    return r;
}

// Scalar-base + lane-constant voffset pair load (r5-r7-proven).
__device__ __forceinline__ void gload_pair(f32x4& a, f32x4& b, const float* sbase, int voff) {
    asm volatile("global_load_dwordx4 %0, %2, %3\n\t"
                 "global_load_dwordx4 %1, %2, %3 offset:16"
                 : "=&v"(a), "=&v"(b) : "v"(voff), "s"(sbase));
}

// Counted waits; "+v" ties give consumers true SSA deps on the wait (rule-#18 safe).
#define WAIT_TIE2(N, a, b) \
    asm volatile("s_waitcnt vmcnt(" #N ")" : "+v"(a), "+v"(b))
#define WAIT_TIE4(N, a, b, c, d) \
    asm volatile("s_waitcnt vmcnt(" #N ")" : "+v"(a), "+v"(b), "+v"(c), "+v"(d))

#define MFMA(a,b,c) __builtin_amdgcn_mfma_f32_16x16x32_bf16((a),(b),(c),0,0,0)

// FINAL (= r7, 23.42us proven): one wave = 16 batches, no LDS, no barriers,
// 64-thread blocks, 1 wave/CU. MFMA 16x16x32 layouts (validated r2-r14):
// A: lane(q,c) holds A[m=c, k=q*8+e]; B: B[k=q*8+e, n=c]; D: D[m=q*4+r, n=c].
// A-row permutation trick: MFMA0 A rows = W[(m>>2)*8+(m&3)], MFMA1 = +4, so
// lane (q,c)'s D regs hold h_new[q*8+0..7] of batch c == next step's B fragment.
// Closed axes: issue-thinning (r9 neutral), chain restructure (r10 -3us),
// 256-thread packing (r11 wrong/r12/r13 abort), redundant blocks (r14 2x slower).
__global__ __launch_bounds__(64, 1)
void rnn_final(const float* __restrict__ x,
               const float* __restrict__ h0p,
               const float* __restrict__ W_ih,
               const float* __restrict__ W_hh,
               const float* __restrict__ b_ih,
               const float* __restrict__ b_hh,
               const float* __restrict__ W_out,
               const float* __restrict__ b_out,
               float* __restrict__ out,
               int B, int T)
{
    const int l = threadIdx.x;
    const int q = l >> 4;
    const int c = l & 15;
    const int bglob = blockIdx.x * 16 + c;

    const int rA0 = ((c >> 2) << 3) + (c & 3);   // permuted A-row for MFMA0
    const int rA1 = rA0 + 4;                      // for MFMA1

    // W_hh: split hi+lo (compounding path). W_ih: plain bf16 (r7-proven).
    bf16x8 Whh0h, Whh0l, Whh1h, Whh1l, Wih0, Wih1;
    {
        const f32x4* p;
        p = (const f32x4*)(W_hh + rA0 * HD + q * 8); split_frag(p[0], p[1], Whh0h, Whh0l);
        p = (const f32x4*)(W_hh + rA1 * HD + q * 8); split_frag(p[0], p[1], Whh1h, Whh1l);
        p = (const f32x4*)(W_ih + rA0 * HD + q * 8); Wih0 = to_bf16_frag(p[0], p[1]);
        p = (const f32x4*)(W_ih + rA1 * HD + q * 8); Wih1 = to_bf16_frag(p[0], p[1]);
    }

    f32x4 bias0, bias1;
#pragma unroll
    for (int r = 0; r < 4; ++r) {
        bias0[r] = b_ih[q*8 + r]     + b_hh[q*8 + r];
        bias1[r] = b_ih[q*8 + 4 + r] + b_hh[q*8 + 4 + r];
    }

    // h0 -> plain bf16 B fragment (one-time rounding)
    bf16x8 h_bf;
    {
        const f32x4* p = (const f32x4*)(h0p + (size_t)bglob * HD + q * 8);
        h_bf = to_bf16_frag(p[0], p[1]);
    }

    // lane-constant byte offset; uniform time offset lives in the SGPR base
    const int voff = (int)(((size_t)bglob * T * HD + q * 8) * 4);

    f32x4 xa[DP], xb[DP];
#pragma unroll
    for (int s = 0; s < DP; ++s)
        gload_pair(xa[s], xb[s], x + (size_t)s * HD, voff);

    // xp parity regs: xpA = next even step, xpB = next odd step (2-step slack)
    f32x4 xpA0, xpA1, xpB0, xpB1;
    {
        WAIT_TIE2(22, xa[0], xb[0]);                  // 24 issued, complete pair 0
        bf16x8 xbf = to_bf16_frag(xa[0], xb[0]);
        xpA0 = MFMA(Wih0, xbf, bias0);
        xpA1 = MFMA(Wih1, xbf, bias1);
    }
    {
        WAIT_TIE2(20, xa[1], xb[1]);                  // complete pair 1
        bf16x8 xbf = to_bf16_frag(xa[1], xb[1]);
        xpB0 = MFMA(Wih0, xbf, bias0);
        xpB1 = MFMA(Wih1, xbf, bias1);
    }

    f32x4 hA = {0,0,0,0}, hB = {0,0,0,0};

    // Steady-state ledger (per 2-step group at even t): enter with pairs
    // x[t+2..t+11] in flight (20 loads); issue pairs x[t+12],x[t+13] -> 24;
    // wait vmcnt(20) completes pairs x[t+2],x[t+3]. Lookahead 10 steps.
    for (int t0 = 0; t0 < T; t0 += DP) {
#pragma unroll
        for (int s = 0; s < DP; s += 2) {
            const int t = t0 + s;                     // even
            // ---- recurrence for step t (consumes xpA; hi->lo C-chained) ----
            f32x4 a0 = MFMA(Whh0h, h_bf, xpA0);
            f32x4 a1 = MFMA(Whh1h, h_bf, xpA1);
            a0 = MFMA(Whh0l, h_bf, a0);
            a1 = MFMA(Whh1l, h_bf, a1);

            // ---- refill ring slots s, s+1 with x[t+12], x[t+13] (clamped) ----
            int k1 = t + DP;     k1 = (k1 < T) ? k1 : (T - 1);
            int k2 = t + DP + 1; k2 = (k2 < T) ? k2 : (T - 1);
            gload_pair(xa[s],     xb[s],     x + (size_t)k1 * HD, voff);
            gload_pair(xa[s + 1], xb[s + 1], x + (size_t)k2 * HD, voff);

            // ---- wait for x[t+2], x[t+3] ----
            const int s2 = (s + 2) % DP;
            const int s3 = (s + 3) % DP;
            WAIT_TIE4(20, xa[s2], xb[s2], xa[s3], xb[s3]);

            // ---- xp(t+2) into xpA (off-chain; ~2 steps of slack) ----
            {
                bf16x8 xbf = to_bf16_frag(xa[s2], xb[s2]);
                xpA0 = MFMA(Wih0, xbf, bias0);
                xpA1 = MFMA(Wih1, xbf, bias1);
            }

            // ---- finish step t: pack then packed relu -> h_bf(t+1) ----
            h_bf = pack4(pk_relu(cvtpk_bf16(a0[0], a0[1])),
                         pk_relu(cvtpk_bf16(a0[2], a0[3])),
                         pk_relu(cvtpk_bf16(a1[0], a1[1])),
                         pk_relu(cvtpk_bf16(a1[2], a1[3])));

            // ---- recurrence for step t+1 (consumes xpB) ----
            f32x4 b0 = MFMA(Whh0h, h_bf, xpB0);
            f32x4 b1 = MFMA(Whh1h, h_bf, xpB1);
            b0 = MFMA(Whh0l, h_bf, b0);
            b1 = MFMA(Whh1l, h_bf, b1);

            // ---- xp(t+3) into xpB ----
            {
                bf16x8 xbf = to_bf16_frag(xa[s3], xb[s3]);
                xpB0 = MFMA(Wih0, xbf, bias0);
                xpB1 = MFMA(Wih1, xbf, bias1);
            }

            // ---- finish step t+1 ----
            h_bf = pack4(pk_relu(cvtpk_bf16(b0[0], b0[1])),
                         pk_relu(cvtpk_bf16(b0[2], b0[3])),
                         pk_relu(cvtpk_bf16(b1[0], b1[1])),
                         pk_relu(cvtpk_bf16(b1[2], b1[3])));
            hA = b0; hB = b1;                         // pre-relu f32 of last step
        }
    }

    // epilogue: f32 relu of the final step (keeps hT/pred at full f32 precision)
#pragma unroll
    for (int r = 0; r < 4; ++r) {
        hA[r] = fmaxf(hA[r], 0.0f);
        hB[r] = fmaxf(hB[r], 0.0f);
    }

    // hT: lane holds units q*8+r (hA) and q*8+4+r (hB) of batch c
    float* outh = out + B + (size_t)bglob * HD;
#pragma unroll
    for (int r = 0; r < 4; ++r) {
        outh[q*8 + r]     = hA[r];
        outh[q*8 + 4 + r] = hB[r];
    }
    // pred[b]: partials in lanes {c, c+16, c+32, c+48}
    float p = 0.0f;
#pragma unroll
    for (int r = 0; r < 4; ++r)
        p += hA[r] * W_out[q*8 + r] + hB[r] * W_out[q*8 + 4 + r];
    p += __shfl_xor(p, 16, 64);
    p += __shfl_xor(p, 32, 64);
    if (q == 0) out[bglob] = p + b_out[0];
}

extern "C" void kernel_launch(void* const* d_in, const int* in_sizes, int n_in,
                              void* d_out, int out_size, void* d_ws, size_t ws_size,
                              hipStream_t stream) {
    const float* x      = (const float*)d_in[0];
    const float* hidden = (const float*)d_in[1];
    const float* W_ih   = (const float*)d_in[2];
    const float* W_hh   = (const float*)d_in[3];
    const float* b_ih   = (const float*)d_in[4];
    const float* b_hh   = (const float*)d_in[5];
    const float* W_out  = (const float*)d_in[6];
    const float* b_out  = (const float*)d_in[7];
    float* out = (float*)d_out;

    const int B = in_sizes[1] / HD;          // hidden is (1, B, H)
    const int T = in_sizes[0] / (B * HD);    // x is (B, T, 32); T=168 = 14*DP

    rnn_final<<<dim3(B / 16), dim3(64), 0, stream>>>(
        x, hidden, W_ih, W_hh, b_ih, b_hh, W_out, b_out, out, B, T);
}